// Round 9
// baseline (187.612 us; speedup 1.0000x reference)
//
#include <hip/hip_runtime.h>

// SelfAttention3D: B=4, C=HID=128, N=16^3=4096.
// R19: 64i/wave kernel (R17) at NSL=8 -> grid 512 = 2 blocks/CU. Completes
// the experiment matrix: R17 proved halved LDS volume (bank conflicts
// exactly halved) but ran at 1 block/CU (TLP starvation, 53.6); R16 proved
// 512 blocks = 2/CU is the TLP sweet spot. This is the untested quadrant:
// halved volume AND restored TLP. Cost (known, R16): Opart 32MB -> mf +4us.
// Single-buffered Kt/Vt with 2 barriers/tile (R18's dbuf was null-negative).
// Structure: 32x32x16 MFMA, two i-groups/wave sharing every K/V LDS read,
// P in registers via permlane32_swap, setprio, bijective XCD swizzle.
// Workspace layout:
//   [0,4M)    Obuf bf16 [b][h][n]  (NSL==1 path only)
//   [4,8M)    Qb bf16 [b][n][h]    (pre-scaled by log2e)
//   [8,12M)   Kb bf16 [b][n][h]
//   [12,16M)  Vb bf16 [b][h][n]
//   [16M+128K,+640K) lpart f32 [NSL*4][4096]
//   [17M, 17M+NSL*4M) Opart bf16 [NSL*4][128][4096]   (NSL=8: 32M, ws>=49M)

#define NV 4096
#define LOG2E 1.44269504088896340736f
#define EPSV 1e-5f

typedef float f32x4 __attribute__((ext_vector_type(4)));
typedef float f32x16 __attribute__((ext_vector_type(16)));
typedef short bf16x8 __attribute__((ext_vector_type(8)));
typedef unsigned short u16x4 __attribute__((ext_vector_type(4)));
typedef unsigned short u16x8 __attribute__((ext_vector_type(8)));

static __device__ __forceinline__ unsigned short f2bf(float f) {
    union { float f; unsigned u; } v; v.f = f;
    unsigned r = v.u + 0x7FFFu + ((v.u >> 16) & 1u);   // RNE
    return (unsigned short)(r >> 16);
}
static __device__ __forceinline__ float bf2f(unsigned short u) {
    union { unsigned u; float f; } v; v.u = ((unsigned)u) << 16; return v.f;
}
static __device__ __forceinline__ unsigned fbits(float f) {
    union { float f; unsigned u; } v; v.f = f; return v.u;
}

// exp2 + row-sum + bf16 pack + cross-half redistribute for one 32x32 S^T tile.
static __device__ __forceinline__ void softmax_pack(
    const f32x16& a, float& lsum, bf16x8& paLo, bf16x8& paHi)
{
    float e[16];
    #pragma unroll
    for (int r = 0; r < 16; ++r) e[r] = __builtin_amdgcn_exp2f(a[r]);
    lsum += ((e[0] + e[1]) + (e[2] + e[3])) + ((e[4] + e[5]) + (e[6] + e[7]))
          + ((e[8] + e[9]) + (e[10] + e[11])) + ((e[12] + e[13]) + (e[14] + e[15]));
    unsigned wd[8];
    #pragma unroll
    for (int g = 0; g < 8; ++g)
        wd[g] = __builtin_amdgcn_perm(fbits(e[2 * g + 1]), fbits(e[2 * g]),
                                      0x07060302u);
    // redistribute across lane-halves (vdst.hi <-> vsrc.lo), R15-verified wiring
    unsigned a0 = wd[0], a2 = wd[2];
    asm("v_permlane32_swap_b32 %0, %1" : "+v"(a0), "+v"(a2));
    unsigned a1 = wd[1], a3 = wd[3];
    asm("v_permlane32_swap_b32 %0, %1" : "+v"(a1), "+v"(a3));
    unsigned b0 = wd[4], b2 = wd[6];
    asm("v_permlane32_swap_b32 %0, %1" : "+v"(b0), "+v"(b2));
    unsigned b1 = wd[5], b3 = wd[7];
    asm("v_permlane32_swap_b32 %0, %1" : "+v"(b1), "+v"(b3));
    union PW { unsigned w[4]; bf16x8 v; };
    PW p0, p1;
    p0.w[0] = a0; p0.w[1] = a1; p0.w[2] = a2; p0.w[3] = a3;
    p1.w[0] = b0; p1.w[1] = b1; p1.w[2] = b2; p1.w[3] = b3;
    paLo = p0.v; paHi = p1.v;
}

// ---------------- fused x-transpose + W-convert + QKV projection ----------------
// grid 768 = m(3) x b(4) x nchunk(64); block 256 = 4 waves x 16 voxels.
__global__ __launch_bounds__(256) void projx_kernel(
    const float* __restrict__ x,
    const float* __restrict__ Wq, const float* __restrict__ Wk,
    const float* __restrict__ Wv,
    const float* __restrict__ bq, const float* __restrict__ bk,
    const float* __restrict__ bv,
    unsigned short* __restrict__ Qb, unsigned short* __restrict__ Kb,
    unsigned short* __restrict__ Vb)
{
    __shared__ unsigned short xt[64 * 136];           // staging: [n][h] m<2, [h][n] m==2
    __shared__ unsigned short Wl[128 * 136];
    const int bid = blockIdx.x;
    const int m = bid >> 8, b = (bid >> 6) & 3, n0 = (bid & 63) << 6;
    const int t = threadIdx.x, w = t >> 6, lane = t & 63;
    const int quad = lane >> 4, l16 = lane & 15;

    const float* Wm = (m == 0) ? Wq : ((m == 1) ? Wk : Wv);
    const float* bias = (m == 0) ? bq : ((m == 1) ? bk : bv);

    // transpose x[b][c][n0+i4..i4+3] -> xt[i][c] (bf16), float4 loads
    #pragma unroll
    for (int it = 0; it < 8; ++it) {
        const int e = (it << 8) + t;                  // 0..2047
        const int c = e >> 4, i4 = (e & 15) << 2;
        const float4 xv = *(const float4*)(x + (((b << 7) + c) << 12) + n0 + i4);
        xt[(i4 + 0) * 136 + c] = f2bf(xv.x);
        xt[(i4 + 1) * 136 + c] = f2bf(xv.y);
        xt[(i4 + 2) * 136 + c] = f2bf(xv.z);
        xt[(i4 + 3) * 136 + c] = f2bf(xv.w);
    }
    // stage W_m f32 -> Wl bf16 [h][c]
    #pragma unroll
    for (int it = 0; it < 16; ++it) {
        const int idx = it * 1024 + (t << 2);
        const float4 wv4 = *(const float4*)(Wm + idx);
        const int h = idx >> 7, c = idx & 127;
        u16x4 pk;
        pk[0] = f2bf(wv4.x); pk[1] = f2bf(wv4.y);
        pk[2] = f2bf(wv4.z); pk[3] = f2bf(wv4.w);
        *(u16x4*)(Wl + h * 136 + c) = pk;
    }
    __syncthreads();

    bf16x8 af[4];
    {
        const int il = (w << 4) + l16;
        #pragma unroll
        for (int ck = 0; ck < 4; ++ck)
            af[ck] = *(const bf16x8*)(xt + il * 136 + (ck << 5) + (quad << 3));
    }
    if (m == 2) __syncthreads();

    #pragma unroll
    for (int s = 0; s < 8; ++s) {
        const int h = (s << 4) + l16;
        f32x4 acc = {0.f, 0.f, 0.f, 0.f};
        #pragma unroll
        for (int ck = 0; ck < 4; ++ck) {
            const bf16x8 wf = *(const bf16x8*)(Wl + h * 136 + (ck << 5) + (quad << 3));
            acc = __builtin_amdgcn_mfma_f32_16x16x32_bf16(af[ck], wf, acc, 0, 0, 0);
        }
        const float bval = bias[h];
        if (m == 2) {
            #pragma unroll
            for (int r = 0; r < 4; ++r)
                xt[h * 66 + (w << 4) + (quad << 2) + r] = f2bf(acc[r] + bval);
        } else {
            #pragma unroll
            for (int r = 0; r < 4; ++r) {
                float val = acc[r] + bval;
                if (m == 0) val *= LOG2E;             // fold softmax exp2 scale into Q
                xt[((w << 4) + (quad << 2) + r) * 136 + h] = f2bf(val);
            }
        }
    }
    __syncthreads();
    if (m == 2) {
        #pragma unroll
        for (int it = 0; it < 32; ++it) {
            const int e = it * 256 + t;
            const int h = e >> 6, il = e & 63;
            Vb[(((b << 7) + h) << 12) + n0 + il] = xt[h * 66 + il];
        }
    } else {
        unsigned short* dst = (m == 0) ? Qb : Kb;
        #pragma unroll
        for (int it = 0; it < 4; ++it) {
            const int e = (it << 8) + t;
            const int row = e >> 4, c8 = (e & 15) << 3;
            *(bf16x8*)(dst + (((b << 12) + n0 + row) << 7) + c8) =
                *(const bf16x8*)(xt + row * 136 + c8);
        }
    }
}

// ---------------- flash attention (32x32 MFMA, 64 i/wave, P in registers) ----------------
// grid NSL*64; bijective XCD swizzle. block 256 = 4 waves; wave owns 64 i
// (two i-groups sharing every K/V LDS read). Per tile (64 j): 2 jt-subtiles;
// each: QK 2x8 mfma (2 indep chains) -> 2x softmax_pack -> PV 2x8 mfma.
// Kt/Vt single-buffered, 2 barriers/tile, reg-prefetch of next tile.
template<int NSL>
__global__ __launch_bounds__(256, 2) void flash_kernel(
    const unsigned short* __restrict__ Qb,
    const unsigned short* __restrict__ Kb,
    const unsigned short* __restrict__ Vb,
    unsigned short* __restrict__ Opart, float* __restrict__ lpart,
    unsigned short* __restrict__ Obuf)
{
    __shared__ unsigned short Kt[64 * 128];           // [j][h], 16B-granule swz: slot=g^(j&15)
    __shared__ unsigned short Vt[128 * 64];           // [h][j], 16B-granule swz: slot=g^(h&7)
    constexpr int NB = NSL * 64;
    const int bid = ((blockIdx.x & 7) * (NB >> 3)) + (blockIdx.x >> 3);
    const int sl = bid >> 6, b = (bid >> 4) & 3, ic = bid & 15;
    const int t = threadIdx.x, w = t >> 6, lane = t & 63;
    const int l32 = lane & 31, hi = lane >> 5;
    const int iw = (ic << 8) + (w << 6);              // wave covers 64 i-rows

    const int T = (NV / NSL) >> 6;
    const int jbase = (sl * T) << 6;

    const int ktg = t & 15, ktj = t >> 4;
    const int vtg = t & 7,  vth = t >> 3;
    const int kswz = (ktg ^ ktj) << 3;
    const int vswz = (vtg ^ (vth & 7)) << 3;

    // Q fragments per i-group: lane(l32,hi) holds Q[i][h = 16kc + 8hi + e]
    bf16x8 qf0[8], qf1[8];
    {
        const unsigned short* qp0 = Qb + (((b << 12) + iw + l32) << 7) + (hi << 3);
        const unsigned short* qp1 = qp0 + (32 << 7);
        #pragma unroll
        for (int kc = 0; kc < 8; ++kc) {
            qf0[kc] = *(const bf16x8*)(qp0 + (kc << 4));
            qf1[kc] = *(const bf16x8*)(qp1 + (kc << 4));
        }
    }
    f32x16 Oacc0[4], Oacc1[4];
    #pragma unroll
    for (int ht = 0; ht < 4; ++ht)
        #pragma unroll
        for (int r = 0; r < 16; ++r) { Oacc0[ht][r] = 0.f; Oacc1[ht][r] = 0.f; }
    float lsum0 = 0.f, lsum1 = 0.f;

    const unsigned short* Kbb = Kb + ((long)b << 19);
    const unsigned short* Vbb = Vb + ((long)b << 19);

    // prologue: prefetch tile 0 into regs
    bf16x8 sk[4], sv[4];
    #pragma unroll
    for (int r = 0; r < 4; ++r)
        sk[r] = *(const bf16x8*)(Kbb + ((jbase + (r << 4) + ktj) << 7) + (ktg << 3));
    #pragma unroll
    for (int r = 0; r < 4; ++r)
        sv[r] = *(const bf16x8*)(Vbb + (((r << 5) + vth) << 12) + jbase + (vtg << 3));

    for (int t8 = 0; t8 < T; ++t8) {
        const int j0 = jbase + (t8 << 6);

        __syncthreads();                              // prev tile's LDS reads done
        #pragma unroll
        for (int r = 0; r < 4; ++r)
            *(bf16x8*)(Kt + (((r << 4) + ktj) << 7) + kswz) = sk[r];
        #pragma unroll
        for (int r = 0; r < 4; ++r)
            *(bf16x8*)(Vt + (((r << 5) + vth) << 6) + vswz) = sv[r];
        __syncthreads();                              // tile visible

        if (t8 + 1 < T) {                             // issue next tile's loads now
            const int j1 = j0 + 64;
            #pragma unroll
            for (int r = 0; r < 4; ++r)
                sk[r] = *(const bf16x8*)(Kbb + ((j1 + (r << 4) + ktj) << 7) + (ktg << 3));
            #pragma unroll
            for (int r = 0; r < 4; ++r)
                sv[r] = *(const bf16x8*)(Vbb + (((r << 5) + vth) << 12) + j1 + (vtg << 3));
        }

        #pragma unroll
        for (int jt = 0; jt < 2; ++jt) {
            // ---- S^T tiles = K.Q^T, both i-groups share each kf read ----
            const unsigned short* kr = Kt + (((jt << 5) + l32) << 7);
            f32x16 a0, a1;
            #pragma unroll
            for (int r = 0; r < 16; ++r) { a0[r] = 0.f; a1[r] = 0.f; }
            __builtin_amdgcn_s_setprio(1);
            #pragma unroll
            for (int kc = 0; kc < 8; ++kc) {
                const bf16x8 kf = *(const bf16x8*)(kr + ((((kc << 1) + hi) ^ (l32 & 15)) << 3));
                a0 = __builtin_amdgcn_mfma_f32_32x32x16_bf16(kf, qf0[kc], a0, 0, 0, 0);
                a1 = __builtin_amdgcn_mfma_f32_32x32x16_bf16(kf, qf1[kc], a1, 0, 0, 0);
            }
            __builtin_amdgcn_s_setprio(0);
            bf16x8 pa00, pa01, pa10, pa11;
            softmax_pack(a0, lsum0, pa00, pa01);
            softmax_pack(a1, lsum1, pa10, pa11);
            // ---- O^T += V.P^T, both i-groups share each v read ----
            __builtin_amdgcn_s_setprio(1);
            #pragma unroll
            for (int ht = 0; ht < 4; ++ht) {
                const unsigned short* vr = Vt + (((ht << 5) + l32) << 6);
                const bf16x8 v0 = *(const bf16x8*)(vr + ((((jt << 2) + hi) ^ (l32 & 7)) << 3));
                const bf16x8 v1 = *(const bf16x8*)(vr + ((((jt << 2) + 2 + hi) ^ (l32 & 7)) << 3));
                Oacc0[ht] = __builtin_amdgcn_mfma_f32_32x32x16_bf16(v0, pa00, Oacc0[ht], 0, 0, 0);
                Oacc0[ht] = __builtin_amdgcn_mfma_f32_32x32x16_bf16(v1, pa01, Oacc0[ht], 0, 0, 0);
                Oacc1[ht] = __builtin_amdgcn_mfma_f32_32x32x16_bf16(v0, pa10, Oacc1[ht], 0, 0, 0);
                Oacc1[ht] = __builtin_amdgcn_mfma_f32_32x32x16_bf16(v1, pa11, Oacc1[ht], 0, 0, 0);
            }
            __builtin_amdgcn_s_setprio(0);
        }
    }

    float l0 = lsum0; l0 += __shfl_xor(l0, 32);       // full row sum, both halves
    float l1 = lsum1; l1 += __shfl_xor(l1, 32);

    if (NSL == 1) {
        const float rl0 = 1.f / l0, rl1 = 1.f / l1;
        #pragma unroll
        for (int ht = 0; ht < 4; ++ht)
            #pragma unroll
            for (int r = 0; r < 16; ++r) {
                const int h = (ht << 5) + (hi << 2) + (r & 3) + ((r >> 2) << 3);
                Obuf[(((b << 7) + h) << 12) + iw + l32]      = f2bf(Oacc0[ht][r] * rl0);
                Obuf[(((b << 7) + h) << 12) + iw + 32 + l32] = f2bf(Oacc1[ht][r] * rl1);
            }
    } else {
        const int slb = (sl << 2) + b;
        if (!hi) {
            lpart[(slb << 12) + iw + l32]      = l0;
            lpart[(slb << 12) + iw + 32 + l32] = l1;
        }
        unsigned short* Ob = Opart + ((long)slb << 19);
        #pragma unroll
        for (int ht = 0; ht < 4; ++ht)
            #pragma unroll
            for (int r = 0; r < 16; ++r) {
                const int h = (ht << 5) + (hi << 2) + (r & 3) + ((r >> 2) << 3);
                Ob[(h << 12) + iw + l32]      = f2bf(Oacc0[ht][r]);
                Ob[(h << 12) + iw + 32 + l32] = f2bf(Oacc1[ht][r]);
            }
    }
}

// ---------------- merge + BN stats + final, one block per channel ----------------
template<int NSL>
__global__ __launch_bounds__(1024) void mf_kernel(
    const unsigned short* __restrict__ Opart, const float* __restrict__ lpart,
    const float* __restrict__ x, const float* __restrict__ bnw,
    const float* __restrict__ bnb, const float* __restrict__ gammap,
    float* __restrict__ out)
{
    const int h = blockIdx.x;
    const int t = threadIdx.x;
    const int b = t >> 8;
    const int i0 = (t & 255) << 4;

    float A[16], L[16];
    #pragma unroll
    for (int k = 0; k < 16; ++k) { A[k] = 0.f; L[k] = 0.f; }
    #pragma unroll
    for (int sl = 0; sl < NSL; ++sl) {
        const int slb = (sl << 2) + b;
        const u16x8 u0 = *(const u16x8*)(Opart + ((long)slb << 19) + ((long)h << 12) + i0);
        const u16x8 u1 = *(const u16x8*)(Opart + ((long)slb << 19) + ((long)h << 12) + i0 + 8);
        const float* lp = lpart + (slb << 12) + i0;
        #pragma unroll
        for (int k = 0; k < 8; ++k) { A[k] += bf2f(u0[k]); A[8 + k] += bf2f(u1[k]); }
        #pragma unroll
        for (int k = 0; k < 4; ++k) {
            const float4 lv = *(const float4*)(lp + (k << 2));
            L[(k << 2) + 0] += lv.x; L[(k << 2) + 1] += lv.y;
            L[(k << 2) + 2] += lv.z; L[(k << 2) + 3] += lv.w;
        }
    }
    float o[16], s = 0.f, ss = 0.f;
    #pragma unroll
    for (int k = 0; k < 16; ++k) {
        o[k] = A[k] / L[k];
        s += o[k]; ss += o[k] * o[k];
    }
    #pragma unroll
    for (int off = 32; off; off >>= 1) {
        s  += __shfl_down(s, off);
        ss += __shfl_down(ss, off);
    }
    __shared__ float rs[16], rss[16], fin[2];
    const int wid = t >> 6;
    if ((t & 63) == 0) { rs[wid] = s; rss[wid] = ss; }
    __syncthreads();
    if (t == 0) {
        float s2 = 0.f, ss2 = 0.f;
        #pragma unroll
        for (int k = 0; k < 16; ++k) { s2 += rs[k]; ss2 += rss[k]; }
        fin[0] = s2; fin[1] = ss2;
    }
    __syncthreads();
    const float inv = 1.f / 16384.f;
    const float mean = fin[0] * inv;
    const float var  = fin[1] * inv - mean * mean;
    const float g = gammap[0];
    const float scale = bnw[h] * rsqrtf(var + EPSV);
    const float a  = g * scale;
    const float bb = g * (bnb[h] - mean * scale);

    const float* xp = x + (((b << 7) + h) << 12) + i0;
    float* op = out + (((b << 7) + h) << 12) + i0;
    #pragma unroll
    for (int k = 0; k < 4; ++k) {
        const float4 xv = *(const float4*)(xp + (k << 2));
        float4 r;
        r.x = o[(k << 2) + 0] * a + bb + xv.x;
        r.y = o[(k << 2) + 1] * a + bb + xv.y;
        r.z = o[(k << 2) + 2] * a + bb + xv.z;
        r.w = o[(k << 2) + 3] * a + bb + xv.w;
        *(float4*)(op + (k << 2)) = r;
    }
}

// NSL==1 variant: Obuf already normalized bf16
__global__ __launch_bounds__(1024) void mf1_kernel(
    const unsigned short* __restrict__ Obuf,
    const float* __restrict__ x, const float* __restrict__ bnw,
    const float* __restrict__ bnb, const float* __restrict__ gammap,
    float* __restrict__ out)
{
    const int h = blockIdx.x;
    const int t = threadIdx.x;
    const int b = t >> 8;
    const int i0 = (t & 255) << 4;
    const u16x8 u0 = *(const u16x8*)(Obuf + (((b << 7) + h) << 12) + i0);
    const u16x8 u1 = *(const u16x8*)(Obuf + (((b << 7) + h) << 12) + i0 + 8);
    float o[16], s = 0.f, ss = 0.f;
    #pragma unroll
    for (int k = 0; k < 8; ++k) { o[k] = bf2f(u0[k]); o[8 + k] = bf2f(u1[k]); }
    #pragma unroll
    for (int k = 0; k < 16; ++k) { s += o[k]; ss += o[k] * o[k]; }
    #pragma unroll
    for (int off = 32; off; off >>= 1) {
        s  += __shfl_down(s, off);
        ss += __shfl_down(ss, off);
    }
    __shared__ float rs[16], rss[16], fin[2];
    const int wid = t >> 6;
    if ((t & 63) == 0) { rs[wid] = s; rss[wid] = ss; }
    __syncthreads();
    if (t == 0) {
        float s2 = 0.f, ss2 = 0.f;
        #pragma unroll
        for (int k = 0; k < 16; ++k) { s2 += rs[k]; ss2 += rss[k]; }
        fin[0] = s2; fin[1] = ss2;
    }
    __syncthreads();
    const float inv = 1.f / 16384.f;
    const float mean = fin[0] * inv;
    const float var  = fin[1] * inv - mean * mean;
    const float g = gammap[0];
    const float scale = bnw[h] * rsqrtf(var + EPSV);
    const float a  = g * scale;
    const float bb = g * (bnb[h] - mean * scale);
    const float* xp = x + (((b << 7) + h) << 12) + i0;
    float* op = out + (((b << 7) + h) << 12) + i0;
    #pragma unroll
    for (int k = 0; k < 4; ++k) {
        const float4 xv = *(const float4*)(xp + (k << 2));
        float4 r;
        r.x = o[(k << 2) + 0] * a + bb + xv.x;
        r.y = o[(k << 2) + 1] * a + bb + xv.y;
        r.z = o[(k << 2) + 2] * a + bb + xv.z;
        r.w = o[(k << 2) + 3] * a + bb + xv.w;
        *(float4*)(op + (k << 2)) = r;
    }
}

extern "C" void kernel_launch(void* const* d_in, const int* in_sizes, int n_in,
                              void* d_out, int out_size, void* d_ws, size_t ws_size,
                              hipStream_t stream) {
    const float* x   = (const float*)d_in[0];
    const float* Wq  = (const float*)d_in[1];
    const float* bq  = (const float*)d_in[2];
    const float* Wk  = (const float*)d_in[3];
    const float* bk  = (const float*)d_in[4];
    const float* Wv  = (const float*)d_in[5];
    const float* bv  = (const float*)d_in[6];
    const float* bnw = (const float*)d_in[7];
    const float* bnb = (const float*)d_in[8];
    const float* gam = (const float*)d_in[9];
    float* out = (float*)d_out;

    char* ws = (char*)d_ws;
    unsigned short* Obuf = (unsigned short*)(ws);
    unsigned short* Qb   = (unsigned short*)(ws + (4u  << 20));
    unsigned short* Kb   = (unsigned short*)(ws + (8u  << 20));
    unsigned short* Vb   = (unsigned short*)(ws + (12u << 20));
    float*          lpart = (float*)(ws + (16u << 20) + (128u << 10));
    unsigned short* Opart = (unsigned short*)(ws + (17u << 20));

    int nsl = 1;
    if      (ws_size >= (17ull << 20) + (32ull << 20)) nsl = 8;
    else if (ws_size >= (17ull << 20) + (16ull << 20)) nsl = 4;
    else if (ws_size >= (17ull << 20) + (8ull  << 20)) nsl = 2;

    projx_kernel<<<768, 256, 0, stream>>>(x, Wq, Wk, Wv, bq, bk, bv, Qb, Kb, Vb);
    if (nsl == 8) {
        flash_kernel<8><<<512, 256, 0, stream>>>(Qb, Kb, Vb, Opart, lpart, Obuf);
        mf_kernel<8><<<128, 1024, 0, stream>>>(Opart, lpart, x, bnw, bnb, gam, out);
    } else if (nsl == 4) {
        flash_kernel<4><<<256, 256, 0, stream>>>(Qb, Kb, Vb, Opart, lpart, Obuf);
        mf_kernel<4><<<128, 1024, 0, stream>>>(Opart, lpart, x, bnw, bnb, gam, out);
    } else if (nsl == 2) {
        flash_kernel<2><<<128, 256, 0, stream>>>(Qb, Kb, Vb, Opart, lpart, Obuf);
        mf_kernel<2><<<128, 1024, 0, stream>>>(Opart, lpart, x, bnw, bnb, gam, out);
    } else {
        flash_kernel<1><<<64, 256, 0, stream>>>(Qb, Kb, Vb, Opart, lpart, Obuf);
        mf1_kernel<<<128, 1024, 0, stream>>>(Obuf, x, bnw, bnb, gam, out);
    }
}

// Round 10
// 140.575 us; speedup vs baseline: 1.3346x; 1.3346x over previous
//
#include <hip/hip_runtime.h>

// SelfAttention3D: B=4, C=HID=128, N=16^3=4096.
// R20: R15 + tile-PAIR staging (BK=128): two 64-j tiles staged into Kt[2]/
// Vt[2] behind one barrier pair -> barriers 34->18 per block, and both
// tiles' compute is one dependency-free register-dataflow region (4 indep
// QK MFMA chains of ILP vs 2). Tile-internal code/swizzles byte-identical
// to R15 (each tile owns a buffer). LDS 64KB -> still 2 blocks/CU. Prefetch
// sk[8]/sv[8] (~190 unified regs, 2 waves/SIMD ok).
// R19 post-mortem: launch_bounds(256,2) + 64i/wave forced 128-VGPR cap ->
// scratch spills (hbm_bytes 240MB); 64i needs ~308 unified regs -> the
// 64i x 2blocks/CU quadrant is register-infeasible. 64i family closed.
// Structure: 32x32x16 MFMA, P in registers via permlane32_swap, setprio,
// bijective XCD swizzle, NSL=4.
// Workspace layout:
//   [0,4M)    Obuf bf16 [b][h][n]  (NSL==1 path only)
//   [4,8M)    Qb bf16 [b][n][h]    (pre-scaled by log2e)
//   [8,12M)   Kb bf16 [b][n][h]
//   [12,16M)  Vb bf16 [b][h][n]
//   [16M+128K,+640K) lpart f32 [NSL*4][4096]
//   [17M, 17M+NSL*4M) Opart bf16 [NSL*4][128][4096]

#define NV 4096
#define LOG2E 1.44269504088896340736f
#define EPSV 1e-5f

typedef float f32x4 __attribute__((ext_vector_type(4)));
typedef float f32x16 __attribute__((ext_vector_type(16)));
typedef short bf16x8 __attribute__((ext_vector_type(8)));
typedef unsigned short u16x4 __attribute__((ext_vector_type(4)));
typedef unsigned short u16x8 __attribute__((ext_vector_type(8)));

static __device__ __forceinline__ unsigned short f2bf(float f) {
    union { float f; unsigned u; } v; v.f = f;
    unsigned r = v.u + 0x7FFFu + ((v.u >> 16) & 1u);   // RNE
    return (unsigned short)(r >> 16);
}
static __device__ __forceinline__ float bf2f(unsigned short u) {
    union { unsigned u; float f; } v; v.u = ((unsigned)u) << 16; return v.f;
}
static __device__ __forceinline__ unsigned fbits(float f) {
    union { float f; unsigned u; } v; v.f = f; return v.u;
}

// ---------------- fused x-transpose + W-convert + QKV projection ----------------
// grid 768 = m(3) x b(4) x nchunk(64); block 256 = 4 waves x 16 voxels.
__global__ __launch_bounds__(256) void projx_kernel(
    const float* __restrict__ x,
    const float* __restrict__ Wq, const float* __restrict__ Wk,
    const float* __restrict__ Wv,
    const float* __restrict__ bq, const float* __restrict__ bk,
    const float* __restrict__ bv,
    unsigned short* __restrict__ Qb, unsigned short* __restrict__ Kb,
    unsigned short* __restrict__ Vb)
{
    __shared__ unsigned short xt[64 * 136];           // staging: [n][h] m<2, [h][n] m==2
    __shared__ unsigned short Wl[128 * 136];
    const int bid = blockIdx.x;
    const int m = bid >> 8, b = (bid >> 6) & 3, n0 = (bid & 63) << 6;
    const int t = threadIdx.x, w = t >> 6, lane = t & 63;
    const int quad = lane >> 4, l16 = lane & 15;

    const float* Wm = (m == 0) ? Wq : ((m == 1) ? Wk : Wv);
    const float* bias = (m == 0) ? bq : ((m == 1) ? bk : bv);

    // transpose x[b][c][n0+i4..i4+3] -> xt[i][c] (bf16), float4 loads
    #pragma unroll
    for (int it = 0; it < 8; ++it) {
        const int e = (it << 8) + t;                  // 0..2047
        const int c = e >> 4, i4 = (e & 15) << 2;
        const float4 xv = *(const float4*)(x + (((b << 7) + c) << 12) + n0 + i4);
        xt[(i4 + 0) * 136 + c] = f2bf(xv.x);
        xt[(i4 + 1) * 136 + c] = f2bf(xv.y);
        xt[(i4 + 2) * 136 + c] = f2bf(xv.z);
        xt[(i4 + 3) * 136 + c] = f2bf(xv.w);
    }
    // stage W_m f32 -> Wl bf16 [h][c]
    #pragma unroll
    for (int it = 0; it < 16; ++it) {
        const int idx = it * 1024 + (t << 2);
        const float4 wv4 = *(const float4*)(Wm + idx);
        const int h = idx >> 7, c = idx & 127;
        u16x4 pk;
        pk[0] = f2bf(wv4.x); pk[1] = f2bf(wv4.y);
        pk[2] = f2bf(wv4.z); pk[3] = f2bf(wv4.w);
        *(u16x4*)(Wl + h * 136 + c) = pk;
    }
    __syncthreads();

    bf16x8 af[4];
    {
        const int il = (w << 4) + l16;
        #pragma unroll
        for (int ck = 0; ck < 4; ++ck)
            af[ck] = *(const bf16x8*)(xt + il * 136 + (ck << 5) + (quad << 3));
    }
    if (m == 2) __syncthreads();

    #pragma unroll
    for (int s = 0; s < 8; ++s) {
        const int h = (s << 4) + l16;
        f32x4 acc = {0.f, 0.f, 0.f, 0.f};
        #pragma unroll
        for (int ck = 0; ck < 4; ++ck) {
            const bf16x8 wf = *(const bf16x8*)(Wl + h * 136 + (ck << 5) + (quad << 3));
            acc = __builtin_amdgcn_mfma_f32_16x16x32_bf16(af[ck], wf, acc, 0, 0, 0);
        }
        const float bval = bias[h];
        if (m == 2) {
            #pragma unroll
            for (int r = 0; r < 4; ++r)
                xt[h * 66 + (w << 4) + (quad << 2) + r] = f2bf(acc[r] + bval);
        } else {
            #pragma unroll
            for (int r = 0; r < 4; ++r) {
                float val = acc[r] + bval;
                if (m == 0) val *= LOG2E;             // fold softmax exp2 scale into Q
                xt[((w << 4) + (quad << 2) + r) * 136 + h] = f2bf(val);
            }
        }
    }
    __syncthreads();
    if (m == 2) {
        #pragma unroll
        for (int it = 0; it < 32; ++it) {
            const int e = it * 256 + t;
            const int h = e >> 6, il = e & 63;
            Vb[(((b << 7) + h) << 12) + n0 + il] = xt[h * 66 + il];
        }
    } else {
        unsigned short* dst = (m == 0) ? Qb : Kb;
        #pragma unroll
        for (int it = 0; it < 4; ++it) {
            const int e = (it << 8) + t;
            const int row = e >> 4, c8 = (e & 15) << 3;
            *(bf16x8*)(dst + (((b << 12) + n0 + row) << 7) + c8) =
                *(const bf16x8*)(xt + row * 136 + c8);
        }
    }
}

// ---------------- flash attention (32x32 MFMA, tile-pair staging) ----------------
// grid NSL*128; bijective XCD swizzle. block 256 = 4 waves; wave owns 32 i.
// Per STAGE (128 j = two 64-j tiles): 1 barrier pair, stage both tiles,
// prefetch next pair, then compute both tiles back-to-back (register
// dataflow, 4 independent QK chains). Tile-internal code identical to R15.
template<int NSL>
__global__ __launch_bounds__(256, 2) void flash_kernel(
    const unsigned short* __restrict__ Qb,
    const unsigned short* __restrict__ Kb,
    const unsigned short* __restrict__ Vb,
    unsigned short* __restrict__ Opart, float* __restrict__ lpart,
    unsigned short* __restrict__ Obuf)
{
    __shared__ unsigned short Kt[2][64 * 128];        // [j][h], 16B-granule swz per buf
    __shared__ unsigned short Vt[2][128 * 64];        // [h][j], 16B-granule swz per buf
    constexpr int NB = NSL * 128;
    const int bid = ((blockIdx.x & 7) * (NB >> 3)) + (blockIdx.x >> 3);
    const int sl = bid >> 7, b = (bid >> 5) & 3, ic = bid & 31;
    const int t = threadIdx.x, lane = t & 63;
    const int l32 = lane & 31, hi = lane >> 5;
    const int iw = (ic << 7) + ((t >> 6) << 5);

    const int T = (NV / NSL) >> 6;                    // even for NSL in {1,2,4}
    const int jbase = (sl * T) << 6;

    const int ktg = t & 15, ktj = t >> 4;
    const int vtg = t & 7,  vth = t >> 3;
    const int kswz = (ktg ^ ktj) << 3;
    const int vswz = (vtg ^ (vth & 7)) << 3;

    // Q fragments: lane(l32,hi) holds Q[i=iw+l32][h = 16kc + 8hi + e]
    bf16x8 qf[8];
    {
        const unsigned short* qp = Qb + (((b << 12) + iw + l32) << 7) + (hi << 3);
        #pragma unroll
        for (int kc = 0; kc < 8; ++kc) qf[kc] = *(const bf16x8*)(qp + (kc << 4));
    }
    f32x16 Oacc[4];
    #pragma unroll
    for (int ht = 0; ht < 4; ++ht)
        #pragma unroll
        for (int r = 0; r < 16; ++r) Oacc[ht][r] = 0.f;
    float lsum = 0.f;

    const unsigned short* Kbb = Kb + ((long)b << 19);
    const unsigned short* Vbb = Vb + ((long)b << 19);

    // one 64-j tile: QK -> softmax_pack -> PV, reading given buffers
    auto compute_tile = [&](const unsigned short* Ktc, const unsigned short* Vtc) {
        #pragma unroll
        for (int jt = 0; jt < 2; ++jt) {
            const unsigned short* kr = Ktc + (((jt << 5) + l32) << 7);
            f32x16 a;
            #pragma unroll
            for (int r = 0; r < 16; ++r) a[r] = 0.f;
            __builtin_amdgcn_s_setprio(1);
            #pragma unroll
            for (int kc = 0; kc < 8; ++kc) {
                const bf16x8 kf = *(const bf16x8*)(kr + ((((kc << 1) + hi) ^ (l32 & 15)) << 3));
                a = __builtin_amdgcn_mfma_f32_32x32x16_bf16(kf, qf[kc], a, 0, 0, 0);
            }
            __builtin_amdgcn_s_setprio(0);
            // lane(l32,hi) holds S^T[j = 32jt + 4hi + (r&3) + 8(r>>2)][i=l32]
            float e[16];
            #pragma unroll
            for (int r = 0; r < 16; ++r) e[r] = __builtin_amdgcn_exp2f(a[r]);
            lsum += ((e[0] + e[1]) + (e[2] + e[3])) + ((e[4] + e[5]) + (e[6] + e[7]))
                  + ((e[8] + e[9]) + (e[10] + e[11])) + ((e[12] + e[13]) + (e[14] + e[15]));
            unsigned wd[8];
            #pragma unroll
            for (int g = 0; g < 8; ++g)
                wd[g] = __builtin_amdgcn_perm(fbits(e[2 * g + 1]), fbits(e[2 * g]),
                                              0x07060302u);
            // redistribute across lane-halves (vdst.hi <-> vsrc.lo), R15-verified
            unsigned a0 = wd[0], a2 = wd[2];
            asm("v_permlane32_swap_b32 %0, %1" : "+v"(a0), "+v"(a2));
            unsigned a1 = wd[1], a3 = wd[3];
            asm("v_permlane32_swap_b32 %0, %1" : "+v"(a1), "+v"(a3));
            unsigned b0 = wd[4], b2 = wd[6];
            asm("v_permlane32_swap_b32 %0, %1" : "+v"(b0), "+v"(b2));
            unsigned b1 = wd[5], b3 = wd[7];
            asm("v_permlane32_swap_b32 %0, %1" : "+v"(b1), "+v"(b3));
            union PW { unsigned w[4]; bf16x8 v; };
            PW p0, p1;
            p0.w[0] = a0; p0.w[1] = a1; p0.w[2] = a2; p0.w[3] = a3;
            p1.w[0] = b0; p1.w[1] = b1; p1.w[2] = b2; p1.w[3] = b3;
            const bf16x8 pa0 = p0.v, pa1 = p1.v;
            __builtin_amdgcn_s_setprio(1);
            #pragma unroll
            for (int ht = 0; ht < 4; ++ht) {
                const unsigned short* vr = Vtc + (((ht << 5) + l32) << 6);
                const bf16x8 v0 = *(const bf16x8*)(vr + ((((jt << 2) + hi) ^ (l32 & 7)) << 3));
                const bf16x8 v1 = *(const bf16x8*)(vr + ((((jt << 2) + 2 + hi) ^ (l32 & 7)) << 3));
                Oacc[ht] = __builtin_amdgcn_mfma_f32_32x32x16_bf16(v0, pa0, Oacc[ht], 0, 0, 0);
                Oacc[ht] = __builtin_amdgcn_mfma_f32_32x32x16_bf16(v1, pa1, Oacc[ht], 0, 0, 0);
            }
            __builtin_amdgcn_s_setprio(0);
        }
    };

    // prologue: prefetch tile-pair 0 into regs (p>>2 = tile in pair, p&3 = r)
    bf16x8 sk[8], sv[8];
    #pragma unroll
    for (int p = 0; p < 8; ++p)
        sk[p] = *(const bf16x8*)(Kbb +
            ((jbase + ((p >> 2) << 6) + (((p & 3) << 4) + ktj)) << 7) + (ktg << 3));
    #pragma unroll
    for (int p = 0; p < 8; ++p)
        sv[p] = *(const bf16x8*)(Vbb + ((((p & 3) << 5) + vth) << 12) +
            jbase + ((p >> 2) << 6) + (vtg << 3));

    const int TP = T >> 1;
    for (int tp = 0; tp < TP; ++tp) {
        __syncthreads();                              // prev pair's LDS reads done
        #pragma unroll
        for (int p = 0; p < 8; ++p)
            *(bf16x8*)(Kt[p >> 2] + ((((p & 3) << 4) + ktj) << 7) + kswz) = sk[p];
        #pragma unroll
        for (int p = 0; p < 8; ++p)
            *(bf16x8*)(Vt[p >> 2] + ((((p & 3) << 5) + vth) << 6) + vswz) = sv[p];
        __syncthreads();                              // pair visible

        if (tp + 1 < TP) {                            // issue next pair's loads now
            const int j1 = jbase + ((tp + 1) << 7);
            #pragma unroll
            for (int p = 0; p < 8; ++p)
                sk[p] = *(const bf16x8*)(Kbb +
                    ((j1 + ((p >> 2) << 6) + (((p & 3) << 4) + ktj)) << 7) + (ktg << 3));
            #pragma unroll
            for (int p = 0; p < 8; ++p)
                sv[p] = *(const bf16x8*)(Vbb + ((((p & 3) << 5) + vth) << 12) +
                    j1 + ((p >> 2) << 6) + (vtg << 3));
        }

        compute_tile(Kt[0], Vt[0]);
        compute_tile(Kt[1], Vt[1]);
    }

    float l = lsum;
    l += __shfl_xor(l, 32);                           // both hi-halves hold i=l32

    if (NSL == 1) {
        const float rl = 1.f / l;
        #pragma unroll
        for (int ht = 0; ht < 4; ++ht)
            #pragma unroll
            for (int r = 0; r < 16; ++r) {
                const int h = (ht << 5) + (hi << 2) + (r & 3) + ((r >> 2) << 3);
                Obuf[(((b << 7) + h) << 12) + iw + l32] = f2bf(Oacc[ht][r] * rl);
            }
    } else {
        const int slb = (sl << 2) + b;
        if (!hi) lpart[(slb << 12) + iw + l32] = l;
        unsigned short* Ob = Opart + ((long)slb << 19);
        #pragma unroll
        for (int ht = 0; ht < 4; ++ht)
            #pragma unroll
            for (int r = 0; r < 16; ++r) {
                const int h = (ht << 5) + (hi << 2) + (r & 3) + ((r >> 2) << 3);
                Ob[(h << 12) + iw + l32] = f2bf(Oacc[ht][r]);
            }
    }
}

// ---------------- merge + BN stats + final, one block per channel ----------------
template<int NSL>
__global__ __launch_bounds__(1024) void mf_kernel(
    const unsigned short* __restrict__ Opart, const float* __restrict__ lpart,
    const float* __restrict__ x, const float* __restrict__ bnw,
    const float* __restrict__ bnb, const float* __restrict__ gammap,
    float* __restrict__ out)
{
    const int h = blockIdx.x;
    const int t = threadIdx.x;
    const int b = t >> 8;
    const int i0 = (t & 255) << 4;

    float A[16], L[16];
    #pragma unroll
    for (int k = 0; k < 16; ++k) { A[k] = 0.f; L[k] = 0.f; }
    #pragma unroll
    for (int sl = 0; sl < NSL; ++sl) {
        const int slb = (sl << 2) + b;
        const u16x8 u0 = *(const u16x8*)(Opart + ((long)slb << 19) + ((long)h << 12) + i0);
        const u16x8 u1 = *(const u16x8*)(Opart + ((long)slb << 19) + ((long)h << 12) + i0 + 8);
        const float* lp = lpart + (slb << 12) + i0;
        #pragma unroll
        for (int k = 0; k < 8; ++k) { A[k] += bf2f(u0[k]); A[8 + k] += bf2f(u1[k]); }
        #pragma unroll
        for (int k = 0; k < 4; ++k) {
            const float4 lv = *(const float4*)(lp + (k << 2));
            L[(k << 2) + 0] += lv.x; L[(k << 2) + 1] += lv.y;
            L[(k << 2) + 2] += lv.z; L[(k << 2) + 3] += lv.w;
        }
    }
    float o[16], s = 0.f, ss = 0.f;
    #pragma unroll
    for (int k = 0; k < 16; ++k) {
        o[k] = A[k] / L[k];
        s += o[k]; ss += o[k] * o[k];
    }
    #pragma unroll
    for (int off = 32; off; off >>= 1) {
        s  += __shfl_down(s, off);
        ss += __shfl_down(ss, off);
    }
    __shared__ float rs[16], rss[16], fin[2];
    const int wid = t >> 6;
    if ((t & 63) == 0) { rs[wid] = s; rss[wid] = ss; }
    __syncthreads();
    if (t == 0) {
        float s2 = 0.f, ss2 = 0.f;
        #pragma unroll
        for (int k = 0; k < 16; ++k) { s2 += rs[k]; ss2 += rss[k]; }
        fin[0] = s2; fin[1] = ss2;
    }
    __syncthreads();
    const float inv = 1.f / 16384.f;
    const float mean = fin[0] * inv;
    const float var  = fin[1] * inv - mean * mean;
    const float g = gammap[0];
    const float scale = bnw[h] * rsqrtf(var + EPSV);
    const float a  = g * scale;
    const float bb = g * (bnb[h] - mean * scale);

    const float* xp = x + (((b << 7) + h) << 12) + i0;
    float* op = out + (((b << 7) + h) << 12) + i0;
    #pragma unroll
    for (int k = 0; k < 4; ++k) {
        const float4 xv = *(const float4*)(xp + (k << 2));
        float4 r;
        r.x = o[(k << 2) + 0] * a + bb + xv.x;
        r.y = o[(k << 2) + 1] * a + bb + xv.y;
        r.z = o[(k << 2) + 2] * a + bb + xv.z;
        r.w = o[(k << 2) + 3] * a + bb + xv.w;
        *(float4*)(op + (k << 2)) = r;
    }
}

// NSL==1 variant: Obuf already normalized bf16
__global__ __launch_bounds__(1024) void mf1_kernel(
    const unsigned short* __restrict__ Obuf,
    const float* __restrict__ x, const float* __restrict__ bnw,
    const float* __restrict__ bnb, const float* __restrict__ gammap,
    float* __restrict__ out)
{
    const int h = blockIdx.x;
    const int t = threadIdx.x;
    const int b = t >> 8;
    const int i0 = (t & 255) << 4;
    const u16x8 u0 = *(const u16x8*)(Obuf + (((b << 7) + h) << 12) + i0);
    const u16x8 u1 = *(const u16x8*)(Obuf + (((b << 7) + h) << 12) + i0 + 8);
    float o[16], s = 0.f, ss = 0.f;
    #pragma unroll
    for (int k = 0; k < 8; ++k) { o[k] = bf2f(u0[k]); o[8 + k] = bf2f(u1[k]); }
    #pragma unroll
    for (int k = 0; k < 16; ++k) { s += o[k]; ss += o[k] * o[k]; }
    #pragma unroll
    for (int off = 32; off; off >>= 1) {
        s  += __shfl_down(s, off);
        ss += __shfl_down(ss, off);
    }
    __shared__ float rs[16], rss[16], fin[2];
    const int wid = t >> 6;
    if ((t & 63) == 0) { rs[wid] = s; rss[wid] = ss; }
    __syncthreads();
    if (t == 0) {
        float s2 = 0.f, ss2 = 0.f;
        #pragma unroll
        for (int k = 0; k < 16; ++k) { s2 += rs[k]; ss2 += rss[k]; }
        fin[0] = s2; fin[1] = ss2;
    }
    __syncthreads();
    const float inv = 1.f / 16384.f;
    const float mean = fin[0] * inv;
    const float var  = fin[1] * inv - mean * mean;
    const float g = gammap[0];
    const float scale = bnw[h] * rsqrtf(var + EPSV);
    const float a  = g * scale;
    const float bb = g * (bnb[h] - mean * scale);
    const float* xp = x + (((b << 7) + h) << 12) + i0;
    float* op = out + (((b << 7) + h) << 12) + i0;
    #pragma unroll
    for (int k = 0; k < 4; ++k) {
        const float4 xv = *(const float4*)(xp + (k << 2));
        float4 r;
        r.x = o[(k << 2) + 0] * a + bb + xv.x;
        r.y = o[(k << 2) + 1] * a + bb + xv.y;
        r.z = o[(k << 2) + 2] * a + bb + xv.z;
        r.w = o[(k << 2) + 3] * a + bb + xv.w;
        *(float4*)(op + (k << 2)) = r;
    }
}

extern "C" void kernel_launch(void* const* d_in, const int* in_sizes, int n_in,
                              void* d_out, int out_size, void* d_ws, size_t ws_size,
                              hipStream_t stream) {
    const float* x   = (const float*)d_in[0];
    const float* Wq  = (const float*)d_in[1];
    const float* bq  = (const float*)d_in[2];
    const float* Wk  = (const float*)d_in[3];
    const float* bk  = (const float*)d_in[4];
    const float* Wv  = (const float*)d_in[5];
    const float* bv  = (const float*)d_in[6];
    const float* bnw = (const float*)d_in[7];
    const float* bnb = (const float*)d_in[8];
    const float* gam = (const float*)d_in[9];
    float* out = (float*)d_out;

    char* ws = (char*)d_ws;
    unsigned short* Obuf = (unsigned short*)(ws);
    unsigned short* Qb   = (unsigned short*)(ws + (4u  << 20));
    unsigned short* Kb   = (unsigned short*)(ws + (8u  << 20));
    unsigned short* Vb   = (unsigned short*)(ws + (12u << 20));
    float*          lpart = (float*)(ws + (16u << 20) + (128u << 10));
    unsigned short* Opart = (unsigned short*)(ws + (17u << 20));

    int nsl = 1;
    if      (ws_size >= (17ull << 20) + (16ull << 20)) nsl = 4;
    else if (ws_size >= (17ull << 20) + (8ull  << 20)) nsl = 2;

    projx_kernel<<<768, 256, 0, stream>>>(x, Wq, Wk, Wv, bq, bk, bv, Qb, Kb, Vb);
    if (nsl == 4) {
        flash_kernel<4><<<512, 256, 0, stream>>>(Qb, Kb, Vb, Opart, lpart, Obuf);
        mf_kernel<4><<<128, 1024, 0, stream>>>(Opart, lpart, x, bnw, bnb, gam, out);
    } else if (nsl == 2) {
        flash_kernel<2><<<256, 256, 0, stream>>>(Qb, Kb, Vb, Opart, lpart, Obuf);
        mf_kernel<2><<<128, 1024, 0, stream>>>(Opart, lpart, x, bnw, bnb, gam, out);
    } else {
        flash_kernel<1><<<128, 256, 0, stream>>>(Qb, Kb, Vb, Opart, lpart, Obuf);
        mf1_kernel<<<128, 1024, 0, stream>>>(Obuf, x, bnw, bnb, gam, out);
    }
}

// Round 11
// 137.648 us; speedup vs baseline: 1.3630x; 1.0213x over previous
//
#include <hip/hip_runtime.h>

// SelfAttention3D: B=4, C=HID=128, N=16^3=4096.
// R21: flash reverted to R15-exact (44.2us; R18 dbuf / R20 tile-pair both
// null -> phase/barrier overhead ruled out, flash sealed). projx: LDS
// x-transpose ELIMINATED - af fragments loaded directly from global via 32
// scalar coalesced loads (column-of-x per lane; x is L3-resident for the
// redundant m=1,2 reads). Deletes 8 dwordx4 + 32 bank-conflicted ds_write_b16
// + 4 ds_read_b128 + 2 barriers per thread. mf: 16 full f32 divides ->
// v_rcp_f32 * mul (~150 VALU/thread saved; rcp err 2^-22 << 0.098 budget).
// Workspace layout:
//   [0,4M)    Obuf bf16 [b][h][n]  (NSL==1 path only)
//   [4,8M)    Qb bf16 [b][n][h]    (pre-scaled by log2e)
//   [8,12M)   Kb bf16 [b][n][h]
//   [12,16M)  Vb bf16 [b][h][n]
//   [16M+128K,+640K) lpart f32 [NSL*4][4096]
//   [17M, 17M+NSL*4M) Opart bf16 [NSL*4][128][4096]

#define NV 4096
#define LOG2E 1.44269504088896340736f
#define EPSV 1e-5f

typedef float f32x4 __attribute__((ext_vector_type(4)));
typedef float f32x16 __attribute__((ext_vector_type(16)));
typedef short bf16x8 __attribute__((ext_vector_type(8)));
typedef unsigned short u16x4 __attribute__((ext_vector_type(4)));
typedef unsigned short u16x8 __attribute__((ext_vector_type(8)));

static __device__ __forceinline__ unsigned short f2bf(float f) {
    union { float f; unsigned u; } v; v.f = f;
    unsigned r = v.u + 0x7FFFu + ((v.u >> 16) & 1u);   // RNE
    return (unsigned short)(r >> 16);
}
static __device__ __forceinline__ float bf2f(unsigned short u) {
    union { unsigned u; float f; } v; v.u = ((unsigned)u) << 16; return v.f;
}
static __device__ __forceinline__ unsigned fbits(float f) {
    union { float f; unsigned u; } v; v.f = f; return v.u;
}

// ---------------- fused W-convert + QKV projection (no x LDS transpose) ----------------
// grid 768 = m(3) x b(4) x nchunk(64); block 256 = 4 waves x 16 voxels.
// af fragments read directly from global x (lane l16 -> consecutive n:
// coalesced 64B segments, 4 c-rows per instruction). xt = output staging only.
__global__ __launch_bounds__(256) void projx_kernel(
    const float* __restrict__ x,
    const float* __restrict__ Wq, const float* __restrict__ Wk,
    const float* __restrict__ Wv,
    const float* __restrict__ bq, const float* __restrict__ bk,
    const float* __restrict__ bv,
    unsigned short* __restrict__ Qb, unsigned short* __restrict__ Kb,
    unsigned short* __restrict__ Vb)
{
    __shared__ unsigned short xt[64 * 136];           // OUTPUT staging: [n][h] m<2, [h][n] m==2
    __shared__ unsigned short Wl[128 * 136];
    const int bid = blockIdx.x;
    const int m = bid >> 8, b = (bid >> 6) & 3, n0 = (bid & 63) << 6;
    const int t = threadIdx.x, w = t >> 6, lane = t & 63;
    const int quad = lane >> 4, l16 = lane & 15;

    const float* Wm = (m == 0) ? Wq : ((m == 1) ? Wk : Wv);
    const float* bias = (m == 0) ? bq : ((m == 1) ? bk : bv);

    // stage W_m f32 -> Wl bf16 [h][c]
    #pragma unroll
    for (int it = 0; it < 16; ++it) {
        const int idx = it * 1024 + (t << 2);
        const float4 wv4 = *(const float4*)(Wm + idx);
        const int h = idx >> 7, c = idx & 127;
        u16x4 pk;
        pk[0] = f2bf(wv4.x); pk[1] = f2bf(wv4.y);
        pk[2] = f2bf(wv4.z); pk[3] = f2bf(wv4.w);
        *(u16x4*)(Wl + h * 136 + c) = pk;
    }

    // af: direct strided-coalesced loads from x (no LDS round trip).
    // lane(l16,quad) holds x^T[n = n0 + 16w + l16][c = 32ck + 8quad + e]
    bf16x8 af[4];
    {
        const int il = (w << 4) + l16;
        const float* xb = x + (((long)(b << 7)) << 12) + n0 + il;
        #pragma unroll
        for (int ck = 0; ck < 4; ++ck) {
            const int c0 = (ck << 5) + (quad << 3);
            union { unsigned short u[8]; bf16x8 v; } pk;
            #pragma unroll
            for (int e = 0; e < 8; ++e)
                pk.u[e] = f2bf(xb[(long)(c0 + e) << 12]);
            af[ck] = pk.v;
        }
    }
    __syncthreads();                                  // Wl visible

    #pragma unroll
    for (int s = 0; s < 8; ++s) {
        const int h = (s << 4) + l16;
        f32x4 acc = {0.f, 0.f, 0.f, 0.f};
        #pragma unroll
        for (int ck = 0; ck < 4; ++ck) {
            const bf16x8 wf = *(const bf16x8*)(Wl + h * 136 + (ck << 5) + (quad << 3));
            acc = __builtin_amdgcn_mfma_f32_16x16x32_bf16(af[ck], wf, acc, 0, 0, 0);
        }
        const float bval = bias[h];
        if (m == 2) {
            #pragma unroll
            for (int r = 0; r < 4; ++r)
                xt[h * 66 + (w << 4) + (quad << 2) + r] = f2bf(acc[r] + bval);
        } else {
            #pragma unroll
            for (int r = 0; r < 4; ++r) {
                float val = acc[r] + bval;
                if (m == 0) val *= LOG2E;             // fold softmax exp2 scale into Q
                xt[((w << 4) + (quad << 2) + r) * 136 + h] = f2bf(val);
            }
        }
    }
    __syncthreads();
    if (m == 2) {
        #pragma unroll
        for (int it = 0; it < 32; ++it) {
            const int e = it * 256 + t;
            const int h = e >> 6, il = e & 63;
            Vb[(((b << 7) + h) << 12) + n0 + il] = xt[h * 66 + il];
        }
    } else {
        unsigned short* dst = (m == 0) ? Qb : Kb;
        #pragma unroll
        for (int it = 0; it < 4; ++it) {
            const int e = (it << 8) + t;
            const int row = e >> 4, c8 = (e & 15) << 3;
            *(bf16x8*)(dst + (((b << 12) + n0 + row) << 7) + c8) =
                *(const bf16x8*)(xt + row * 136 + c8);
        }
    }
}

// ---------------- flash attention (32x32 MFMA, P in registers) — R15-exact ----------------
// grid NSL*128; bijective XCD swizzle. block 256 = 4 waves; wave owns 32 i.
// Per tile (64 j): 2 jt-subtiles; each: QK 8 mfma_32x32x16 -> exp2 -> pack ->
// 4 permlane32_swap -> PV 8 mfma. K/V staged in LDS (single-buffered,
// 2 barriers/tile); next tile reg-prefetched during compute.
template<int NSL>
__global__ __launch_bounds__(256, 2) void flash_kernel(
    const unsigned short* __restrict__ Qb,
    const unsigned short* __restrict__ Kb,
    const unsigned short* __restrict__ Vb,
    unsigned short* __restrict__ Opart, float* __restrict__ lpart,
    unsigned short* __restrict__ Obuf)
{
    __shared__ unsigned short Kt[64 * 128];           // [j][h], 16B-granule swz: slot=g^(j&15)
    __shared__ unsigned short Vt[128 * 64];           // [h][j], 16B-granule swz: slot=g^(h&7)
    constexpr int NB = NSL * 128;
    const int bid = ((blockIdx.x & 7) * (NB >> 3)) + (blockIdx.x >> 3);
    const int sl = bid >> 7, b = (bid >> 5) & 3, ic = bid & 31;
    const int t = threadIdx.x, w = t >> 6, lane = t & 63;
    const int l32 = lane & 31, hi = lane >> 5;
    const int iw = (ic << 7) + (w << 5);

    const int T = (NV / NSL) >> 6;
    const int jbase = (sl * T) << 6;

    const int ktg = t & 15, ktj = t >> 4;
    const int vtg = t & 7,  vth = t >> 3;
    const int kswz = (ktg ^ ktj) << 3;
    const int vswz = (vtg ^ (vth & 7)) << 3;

    // Q fragments: lane(l32,hi) holds Q[i=iw+l32][h = 16kc + 8hi + e]
    bf16x8 qf[8];
    {
        const unsigned short* qp = Qb + (((b << 12) + iw + l32) << 7) + (hi << 3);
        #pragma unroll
        for (int kc = 0; kc < 8; ++kc) qf[kc] = *(const bf16x8*)(qp + (kc << 4));
    }
    f32x16 Oacc[4];
    #pragma unroll
    for (int ht = 0; ht < 4; ++ht)
        #pragma unroll
        for (int r = 0; r < 16; ++r) Oacc[ht][r] = 0.f;
    float lsum = 0.f;

    const unsigned short* Kbb = Kb + ((long)b << 19);
    const unsigned short* Vbb = Vb + ((long)b << 19);

    // prologue: prefetch tile 0 into regs
    bf16x8 sk[4], sv[4];
    #pragma unroll
    for (int r = 0; r < 4; ++r)
        sk[r] = *(const bf16x8*)(Kbb + ((jbase + (r << 4) + ktj) << 7) + (ktg << 3));
    #pragma unroll
    for (int r = 0; r < 4; ++r)
        sv[r] = *(const bf16x8*)(Vbb + (((r << 5) + vth) << 12) + jbase + (vtg << 3));

    for (int t8 = 0; t8 < T; ++t8) {
        const int j0 = jbase + (t8 << 6);

        __syncthreads();                              // prev tile's LDS reads done
        #pragma unroll
        for (int r = 0; r < 4; ++r)
            *(bf16x8*)(Kt + (((r << 4) + ktj) << 7) + kswz) = sk[r];
        #pragma unroll
        for (int r = 0; r < 4; ++r)
            *(bf16x8*)(Vt + (((r << 5) + vth) << 6) + vswz) = sv[r];
        __syncthreads();                              // tile visible

        if (t8 + 1 < T) {                             // issue next tile's loads now
            const int j1 = j0 + 64;
            #pragma unroll
            for (int r = 0; r < 4; ++r)
                sk[r] = *(const bf16x8*)(Kbb + ((j1 + (r << 4) + ktj) << 7) + (ktg << 3));
            #pragma unroll
            for (int r = 0; r < 4; ++r)
                sv[r] = *(const bf16x8*)(Vbb + (((r << 5) + vth) << 12) + j1 + (vtg << 3));
        }

        #pragma unroll
        for (int jt = 0; jt < 2; ++jt) {
            // ---- S^T tile = K.Q^T (A = K rows j=32jt+l32, k = 16kc+8hi+e) ----
            const unsigned short* kr = Kt + (((jt << 5) + l32) << 7);
            f32x16 a;
            #pragma unroll
            for (int r = 0; r < 16; ++r) a[r] = 0.f;
            __builtin_amdgcn_s_setprio(1);
            #pragma unroll
            for (int kc = 0; kc < 8; ++kc) {
                const bf16x8 kf = *(const bf16x8*)(kr + ((((kc << 1) + hi) ^ (l32 & 15)) << 3));
                a = __builtin_amdgcn_mfma_f32_32x32x16_bf16(kf, qf[kc], a, 0, 0, 0);
            }
            __builtin_amdgcn_s_setprio(0);
            // lane(l32,hi) holds S^T[j = 32jt + 4hi + (r&3) + 8(r>>2)][i=l32]
            float e[16];
            #pragma unroll
            for (int r = 0; r < 16; ++r) e[r] = __builtin_amdgcn_exp2f(a[r]);
            lsum += ((e[0] + e[1]) + (e[2] + e[3])) + ((e[4] + e[5]) + (e[6] + e[7]))
                  + ((e[8] + e[9]) + (e[10] + e[11])) + ((e[12] + e[13]) + (e[14] + e[15]));
            // pack pairs: wd[g] = bf16{e[2g] lo, e[2g+1] hi}
            unsigned wd[8];
            #pragma unroll
            for (int g = 0; g < 8; ++g)
                wd[g] = __builtin_amdgcn_perm(fbits(e[2 * g + 1]), fbits(e[2 * g]),
                                              0x07060302u);
            // redistribute across lane-halves (vdst.hi <-> vsrc.lo), R15-verified
            unsigned a0 = wd[0], a2 = wd[2];
            asm("v_permlane32_swap_b32 %0, %1" : "+v"(a0), "+v"(a2));
            unsigned a1 = wd[1], a3 = wd[3];
            asm("v_permlane32_swap_b32 %0, %1" : "+v"(a1), "+v"(a3));
            unsigned b0 = wd[4], b2 = wd[6];
            asm("v_permlane32_swap_b32 %0, %1" : "+v"(b0), "+v"(b2));
            unsigned b1 = wd[5], b3 = wd[7];
            asm("v_permlane32_swap_b32 %0, %1" : "+v"(b1), "+v"(b3));
            union PW { unsigned w[4]; bf16x8 v; };
            PW p0, p1;
            p0.w[0] = a0; p0.w[1] = a1; p0.w[2] = a2; p0.w[3] = a3;
            p1.w[0] = b0; p1.w[1] = b1; p1.w[2] = b2; p1.w[3] = b3;
            const bf16x8 pa0 = p0.v, pa1 = p1.v;
            // ---- O^T += V.P^T (A = V rows h=32ht+l32, k = j; B = pa) ----
            __builtin_amdgcn_s_setprio(1);
            #pragma unroll
            for (int ht = 0; ht < 4; ++ht) {
                const unsigned short* vr = Vt + (((ht << 5) + l32) << 6);
                const bf16x8 v0 = *(const bf16x8*)(vr + ((((jt << 2) + hi) ^ (l32 & 7)) << 3));
                const bf16x8 v1 = *(const bf16x8*)(vr + ((((jt << 2) + 2 + hi) ^ (l32 & 7)) << 3));
                Oacc[ht] = __builtin_amdgcn_mfma_f32_32x32x16_bf16(v0, pa0, Oacc[ht], 0, 0, 0);
                Oacc[ht] = __builtin_amdgcn_mfma_f32_32x32x16_bf16(v1, pa1, Oacc[ht], 0, 0, 0);
            }
            __builtin_amdgcn_s_setprio(0);
        }
    }

    float l = lsum;
    l += __shfl_xor(l, 32);                           // both hi-halves hold i=l32

    if (NSL == 1) {
        const float rl = 1.f / l;
        #pragma unroll
        for (int ht = 0; ht < 4; ++ht)
            #pragma unroll
            for (int r = 0; r < 16; ++r) {
                const int h = (ht << 5) + (hi << 2) + (r & 3) + ((r >> 2) << 3);
                Obuf[(((b << 7) + h) << 12) + iw + l32] = f2bf(Oacc[ht][r] * rl);
            }
    } else {
        const int slb = (sl << 2) + b;
        if (!hi) lpart[(slb << 12) + iw + l32] = l;
        unsigned short* Ob = Opart + ((long)slb << 19);
        #pragma unroll
        for (int ht = 0; ht < 4; ++ht)
            #pragma unroll
            for (int r = 0; r < 16; ++r) {
                const int h = (ht << 5) + (hi << 2) + (r & 3) + ((r >> 2) << 3);
                Ob[(h << 12) + iw + l32] = f2bf(Oacc[ht][r]);
            }
    }
}

// ---------------- merge + BN stats + final, one block per channel ----------------
template<int NSL>
__global__ __launch_bounds__(1024) void mf_kernel(
    const unsigned short* __restrict__ Opart, const float* __restrict__ lpart,
    const float* __restrict__ x, const float* __restrict__ bnw,
    const float* __restrict__ bnb, const float* __restrict__ gammap,
    float* __restrict__ out)
{
    const int h = blockIdx.x;
    const int t = threadIdx.x;
    const int b = t >> 8;
    const int i0 = (t & 255) << 4;

    float A[16], L[16];
    #pragma unroll
    for (int k = 0; k < 16; ++k) { A[k] = 0.f; L[k] = 0.f; }
    #pragma unroll
    for (int sl = 0; sl < NSL; ++sl) {
        const int slb = (sl << 2) + b;
        const u16x8 u0 = *(const u16x8*)(Opart + ((long)slb << 19) + ((long)h << 12) + i0);
        const u16x8 u1 = *(const u16x8*)(Opart + ((long)slb << 19) + ((long)h << 12) + i0 + 8);
        const float* lp = lpart + (slb << 12) + i0;
        #pragma unroll
        for (int k = 0; k < 8; ++k) { A[k] += bf2f(u0[k]); A[8 + k] += bf2f(u1[k]); }
        #pragma unroll
        for (int k = 0; k < 4; ++k) {
            const float4 lv = *(const float4*)(lp + (k << 2));
            L[(k << 2) + 0] += lv.x; L[(k << 2) + 1] += lv.y;
            L[(k << 2) + 2] += lv.z; L[(k << 2) + 3] += lv.w;
        }
    }
    float o[16], s = 0.f, ss = 0.f;
    #pragma unroll
    for (int k = 0; k < 16; ++k) {
        o[k] = A[k] * __builtin_amdgcn_rcpf(L[k]);    // rcp: ~1ulp, << absmax budget
        s += o[k]; ss += o[k] * o[k];
    }
    #pragma unroll
    for (int off = 32; off; off >>= 1) {
        s  += __shfl_down(s, off);
        ss += __shfl_down(ss, off);
    }
    __shared__ float rs[16], rss[16], fin[2];
    const int wid = t >> 6;
    if ((t & 63) == 0) { rs[wid] = s; rss[wid] = ss; }
    __syncthreads();
    if (t == 0) {
        float s2 = 0.f, ss2 = 0.f;
        #pragma unroll
        for (int k = 0; k < 16; ++k) { s2 += rs[k]; ss2 += rss[k]; }
        fin[0] = s2; fin[1] = ss2;
    }
    __syncthreads();
    const float inv = 1.f / 16384.f;
    const float mean = fin[0] * inv;
    const float var  = fin[1] * inv - mean * mean;
    const float g = gammap[0];
    const float scale = bnw[h] * rsqrtf(var + EPSV);
    const float a  = g * scale;
    const float bb = g * (bnb[h] - mean * scale);

    const float* xp = x + (((b << 7) + h) << 12) + i0;
    float* op = out + (((b << 7) + h) << 12) + i0;
    #pragma unroll
    for (int k = 0; k < 4; ++k) {
        const float4 xv = *(const float4*)(xp + (k << 2));
        float4 r;
        r.x = o[(k << 2) + 0] * a + bb + xv.x;
        r.y = o[(k << 2) + 1] * a + bb + xv.y;
        r.z = o[(k << 2) + 2] * a + bb + xv.z;
        r.w = o[(k << 2) + 3] * a + bb + xv.w;
        *(float4*)(op + (k << 2)) = r;
    }
}

// NSL==1 variant: Obuf already normalized bf16
__global__ __launch_bounds__(1024) void mf1_kernel(
    const unsigned short* __restrict__ Obuf,
    const float* __restrict__ x, const float* __restrict__ bnw,
    const float* __restrict__ bnb, const float* __restrict__ gammap,
    float* __restrict__ out)
{
    const int h = blockIdx.x;
    const int t = threadIdx.x;
    const int b = t >> 8;
    const int i0 = (t & 255) << 4;
    const u16x8 u0 = *(const u16x8*)(Obuf + (((b << 7) + h) << 12) + i0);
    const u16x8 u1 = *(const u16x8*)(Obuf + (((b << 7) + h) << 12) + i0 + 8);
    float o[16], s = 0.f, ss = 0.f;
    #pragma unroll
    for (int k = 0; k < 8; ++k) { o[k] = bf2f(u0[k]); o[8 + k] = bf2f(u1[k]); }
    #pragma unroll
    for (int k = 0; k < 16; ++k) { s += o[k]; ss += o[k] * o[k]; }
    #pragma unroll
    for (int off = 32; off; off >>= 1) {
        s  += __shfl_down(s, off);
        ss += __shfl_down(ss, off);
    }
    __shared__ float rs[16], rss[16], fin[2];
    const int wid = t >> 6;
    if ((t & 63) == 0) { rs[wid] = s; rss[wid] = ss; }
    __syncthreads();
    if (t == 0) {
        float s2 = 0.f, ss2 = 0.f;
        #pragma unroll
        for (int k = 0; k < 16; ++k) { s2 += rs[k]; ss2 += rss[k]; }
        fin[0] = s2; fin[1] = ss2;
    }
    __syncthreads();
    const float inv = 1.f / 16384.f;
    const float mean = fin[0] * inv;
    const float var  = fin[1] * inv - mean * mean;
    const float g = gammap[0];
    const float scale = bnw[h] * rsqrtf(var + EPSV);
    const float a  = g * scale;
    const float bb = g * (bnb[h] - mean * scale);
    const float* xp = x + (((b << 7) + h) << 12) + i0;
    float* op = out + (((b << 7) + h) << 12) + i0;
    #pragma unroll
    for (int k = 0; k < 4; ++k) {
        const float4 xv = *(const float4*)(xp + (k << 2));
        float4 r;
        r.x = o[(k << 2) + 0] * a + bb + xv.x;
        r.y = o[(k << 2) + 1] * a + bb + xv.y;
        r.z = o[(k << 2) + 2] * a + bb + xv.z;
        r.w = o[(k << 2) + 3] * a + bb + xv.w;
        *(float4*)(op + (k << 2)) = r;
    }
}

extern "C" void kernel_launch(void* const* d_in, const int* in_sizes, int n_in,
                              void* d_out, int out_size, void* d_ws, size_t ws_size,
                              hipStream_t stream) {
    const float* x   = (const float*)d_in[0];
    const float* Wq  = (const float*)d_in[1];
    const float* bq  = (const float*)d_in[2];
    const float* Wk  = (const float*)d_in[3];
    const float* bk  = (const float*)d_in[4];
    const float* Wv  = (const float*)d_in[5];
    const float* bv  = (const float*)d_in[6];
    const float* bnw = (const float*)d_in[7];
    const float* bnb = (const float*)d_in[8];
    const float* gam = (const float*)d_in[9];
    float* out = (float*)d_out;

    char* ws = (char*)d_ws;
    unsigned short* Obuf = (unsigned short*)(ws);
    unsigned short* Qb   = (unsigned short*)(ws + (4u  << 20));
    unsigned short* Kb   = (unsigned short*)(ws + (8u  << 20));
    unsigned short* Vb   = (unsigned short*)(ws + (12u << 20));
    float*          lpart = (float*)(ws + (16u << 20) + (128u << 10));
    unsigned short* Opart = (unsigned short*)(ws + (17u << 20));

    int nsl = 1;
    if      (ws_size >= (17ull << 20) + (16ull << 20)) nsl = 4;
    else if (ws_size >= (17ull << 20) + (8ull  << 20)) nsl = 2;

    projx_kernel<<<768, 256, 0, stream>>>(x, Wq, Wk, Wv, bq, bk, bv, Qb, Kb, Vb);
    if (nsl == 4) {
        flash_kernel<4><<<512, 256, 0, stream>>>(Qb, Kb, Vb, Opart, lpart, Obuf);
        mf_kernel<4><<<128, 1024, 0, stream>>>(Opart, lpart, x, bnw, bnb, gam, out);
    } else if (nsl == 2) {
        flash_kernel<2><<<256, 256, 0, stream>>>(Qb, Kb, Vb, Opart, lpart, Obuf);
        mf_kernel<2><<<128, 1024, 0, stream>>>(Opart, lpart, x, bnw, bnb, gam, out);
    } else {
        flash_kernel<1><<<128, 256, 0, stream>>>(Qb, Kb, Vb, Opart, lpart, Obuf);
        mf1_kernel<<<128, 1024, 0, stream>>>(Obuf, x, bnw, bnb, gam, out);
    }
}